// Round 3
// baseline (206.926 us; speedup 1.0000x reference)
//
#include <hip/hip_runtime.h>
#include <math.h>

// Problem constants
#define HD    64
#define NIN   1535
#define NN    1536
#define BB    32
#define BN_EPS 1e-5f
#define CH    64     // rows per chunk
#define NCH   24     // chunks per batch
#define NBLK  (BB * NCH)   // 768

// Workspace layout (floats): M[768], S[768], vec[768][64], counter
#define WS_M   0
#define WS_S   768
#define WS_V   1536
#define WS_CNT 50688               // uint32 done-counter (float index)
#define CNT_BYTE_OFF (WS_CNT * 4)

// ---- shared-memory overlay (float offsets into S[10880] = 43.5 KB) ----
// main phase
#define SM_W1  0      // [64][9]
#define SM_B1  576
#define SM_B2  640
#define SM_BE  704
#define SM_U   768
#define SM_WE  832    // [64][8]
#define SM_W2T 1344   // [64][65] W2T[k][h]
#define SM_X   5504   // [64][8]
#define SM_Y   6016
#define SM_H1  6080   // [4][64]
#define SM_H2  6336   // [64][64]
#define SM_SK  10432
#define SM_E   10496
#define SM_RB  10560  // [256]
#define SM_R0  10816
// tail phase (only the last-finishing block runs this; overlays main regions)
#define ST_WAVT 0     // [64][64] WAVT[k][h]
#define ST_BAV  4096
#define ST_ML   4160  // [768]
#define ST_SL   4928  // [768]
#define ST_WX   5696  // [768]
#define ST_MB   6464
#define ST_ISB  6496
#define ST_WA   6528  // [64][65] staging (dead after fold)
#define ST_ST   6528  // [32][66] (reuses WA region)
#define ST_ZS   8640  // [32][66]
#define ST_SC   10752
#define ST_SH   10816
#define SMEM_F  10880

__global__ __launch_bounds__(256) void k_fused(
    const float* __restrict__ xx, const float* __restrict__ yy,
    const float* __restrict__ oxx,
    const float* __restrict__ W1, const float* __restrict__ b1,
    const float* __restrict__ W2, const float* __restrict__ b2,
    const float* __restrict__ Wenc, const float* __restrict__ benc,
    const float* __restrict__ WK, const float* __restrict__ wQKk,
    const float* __restrict__ WV, const float* __restrict__ bV,
    const float* __restrict__ WA, const float* __restrict__ bA,
    const float* __restrict__ gamma, const float* __restrict__ beta,
    const float* __restrict__ Wmu, const float* __restrict__ bmu,
    const float* __restrict__ Wsig, const float* __restrict__ bsig,
    float* __restrict__ ws, unsigned int* __restrict__ cnt,
    float* __restrict__ out) {
  __shared__ float S[SMEM_F];
  const int t = threadIdx.x;
  const int blk = blockIdx.x;
  const int b = blk & 31;
  const int c = blk >> 5;
  const int pp = b * NCH + c;

  // ================= main phase: encode chunk + flash-softmax partial ====
  {
    float* W1s = S + SM_W1;  float* b1s = S + SM_B1;  float* b2s = S + SM_B2;
    float* bencs = S + SM_BE; float* us = S + SM_U;   float* Wencs = S + SM_WE;
    float* W2Ts = S + SM_W2T; float* xs = S + SM_X;   float* ys = S + SM_Y;
    float* h2s = S + SM_H2;   float* sks = S + SM_SK; float* e_s = S + SM_E;
    float* rbuf = S + SM_RB;  float* red0 = S + SM_R0;

    for (int e = t; e < 576; e += 256) W1s[e] = W1[e];
    for (int e = t; e < 512; e += 256) Wencs[e] = Wenc[e];
    for (int e = t; e < 4096; e += 256) {
      int h = e >> 6, k = e & 63;
      W2Ts[k * 65 + h] = W2[e];
    }
    for (int e = t; e < 512; e += 256) {
      int j = e >> 3, k = e & 7;
      int r0 = c * CH + j;
      xs[e] = (r0 < NIN) ? xx[(size_t)b * (NIN * 8) + (size_t)r0 * 8 + k]
                         : oxx[b * 8 + k];
    }
    if (t < 64) {
      b1s[t] = b1[t]; b2s[t] = b2[t]; bencs[t] = benc[t];
      int r0 = c * CH + t;
      ys[t] = (r0 < NIN) ? yy[b * NIN + r0] : 0.f;
      float a = 0.f;
      #pragma unroll
      for (int h0 = 0; h0 < 64; h0++) a += wQKk[h0] * WK[h0 * 64 + t];
      us[t] = a;
    }
    __syncthreads();

    const int w = t >> 6, lane = t & 63;
    float* h1w = S + SM_H1 + w * 64;

    float w2r[64];
    #pragma unroll
    for (int k = 0; k < 64; k++) w2r[k] = W2Ts[k * 65 + lane];

    for (int rr = 0; rr < 16; rr++) {
      int j = w * 16 + rr;
      int r0 = c * CH + j;
      const float* xr = xs + j * 8;
      float h2;
      if (r0 < NIN) {                       // wave-uniform branch
        const float* wr = W1s + lane * 9;
        float a = b1s[lane];
        a += xr[0] * wr[0] + xr[1] * wr[1] + xr[2] * wr[2] + xr[3] * wr[3];
        a += xr[4] * wr[4] + xr[5] * wr[5] + xr[6] * wr[6] + xr[7] * wr[7];
        a += ys[j] * wr[8];
        h1w[lane] = fmaxf(a, 0.f);          // wave-synchronous LDS
        float a0 = b2s[lane], a1 = 0.f;
        #pragma unroll
        for (int k = 0; k < 64; k += 4) {
          float4 hv = *(const float4*)(h1w + k);
          a0 += hv.x * w2r[k]     + hv.z * w2r[k + 2];
          a1 += hv.y * w2r[k + 1] + hv.w * w2r[k + 3];
        }
        h2 = fmaxf(a0 + a1, 0.f);
      } else {                              // output node: enc layer only
        const float* wr = Wencs + lane * 8;
        float a = bencs[lane];
        #pragma unroll
        for (int k = 0; k < 8; k++) a += xr[k] * wr[k];
        h2 = fmaxf(a, 0.f);
      }
      h2s[j * 64 + lane] = h2;
      float p = h2 * us[lane];
      p += __shfl_down(p, 32); p += __shfl_down(p, 16); p += __shfl_down(p, 8);
      p += __shfl_down(p, 4);  p += __shfl_down(p, 2);  p += __shfl_down(p, 1);
      if (lane == 0) sks[j] = p;
    }
    __syncthreads();

    if (t < 64) {
      float m = sks[t];
      m = fmaxf(m, __shfl_down(m, 32)); m = fmaxf(m, __shfl_down(m, 16));
      m = fmaxf(m, __shfl_down(m, 8));  m = fmaxf(m, __shfl_down(m, 4));
      m = fmaxf(m, __shfl_down(m, 2));  m = fmaxf(m, __shfl_down(m, 1));
      if (t == 0) red0[0] = m;
    }
    __syncthreads();
    float M = red0[0];
    if (t < 64) {
      float e = expf(sks[t] - M);
      e_s[t] = e;
      float s = e;
      s += __shfl_down(s, 32); s += __shfl_down(s, 16); s += __shfl_down(s, 8);
      s += __shfl_down(s, 4);  s += __shfl_down(s, 2);  s += __shfl_down(s, 1);
      if (t == 0) { ws[WS_M + pp] = M; ws[WS_S + pp] = s; }
    }
    __syncthreads();
    {
      float acc = 0.f;
      for (int j = w; j < 64; j += 4) acc += e_s[j] * h2s[j * 64 + lane];
      rbuf[t] = acc;
      __syncthreads();
      if (t < 64)
        ws[WS_V + pp * 64 + t] =
            rbuf[t] + rbuf[64 + t] + rbuf[128 + t] + rbuf[192 + t];
    }
  }

  // ================= last-block gate ====================================
  __threadfence();           // release this block's ws writes (device scope)
  __syncthreads();
  if (t == 0) S[SM_R0] = (float)(atomicAdd(cnt, 1u) == NBLK - 1 ? 1 : 0);
  __syncthreads();
  if (S[SM_R0] == 0.f) return;
  __threadfence();           // acquire: all 768 blocks' partials visible
  __syncthreads();

  // ================= tail phase (one block) =============================
  {
    float* WAVT = S + ST_WAVT; float* bAVs = S + ST_BAV;
    float* Ml = S + ST_ML;  float* Sl = S + ST_SL;  float* wexp = S + ST_WX;
    float* Mb = S + ST_MB;  float* iSb = S + ST_ISB;
    float* WAs = S + ST_WA; float* st = S + ST_ST;  float* zs = S + ST_ZS;
    float* scs = S + ST_SC; float* shs = S + ST_SH;

    for (int e = t; e < 4096; e += 256) {
      int h = e >> 6, m = e & 63;
      WAs[h * 65 + m] = WA[e];
    }
    for (int p = t; p < 768; p += 256) {
      Ml[p] = ws[WS_M + p];
      Sl[p] = ws[WS_S + p];
    }
    __syncthreads();

    if (t < 64) {                 // bAV = bA + WA@bV
      float a = bA[t];
      #pragma unroll
      for (int k = 0; k < 64; k++) a += WAs[t * 65 + k] * bV[k];
      bAVs[t] = a;
    }
    if (t < 32) {                 // per-batch max
      float m = -1e30f;
      for (int cc = 0; cc < NCH; cc++) m = fmaxf(m, Ml[t * NCH + cc]);
      Mb[t] = m;
    }
    {                             // fold WAVT[k][h] = (WA@WV)[h][k]
      int kg = t >> 6, h = t & 63;
      float acc[16];
      #pragma unroll
      for (int kk = 0; kk < 16; kk++) acc[kk] = 0.f;
      for (int m = 0; m < 64; m++) {
        float wa = WAs[h * 65 + m];
        // wave-uniform address -> scalar/broadcast loads
        const float4* wv = (const float4*)(WV + m * 64 + kg * 16);
        float4 w0 = wv[0], w1 = wv[1], w2 = wv[2], w3 = wv[3];
        acc[0]  += wa * w0.x; acc[1]  += wa * w0.y; acc[2]  += wa * w0.z; acc[3]  += wa * w0.w;
        acc[4]  += wa * w1.x; acc[5]  += wa * w1.y; acc[6]  += wa * w1.z; acc[7]  += wa * w1.w;
        acc[8]  += wa * w2.x; acc[9]  += wa * w2.y; acc[10] += wa * w2.z; acc[11] += wa * w2.w;
        acc[12] += wa * w3.x; acc[13] += wa * w3.y; acc[14] += wa * w3.z; acc[15] += wa * w3.w;
      }
      #pragma unroll
      for (int kk = 0; kk < 16; kk++) WAVT[(kg * 16 + kk) * 64 + h] = acc[kk];
    }
    __syncthreads();
    for (int p = t; p < 768; p += 256) wexp[p] = expf(Ml[p] - Mb[p / NCH]);
    __syncthreads();
    if (t < 32) {
      float s = 0.f;
      for (int cc = 0; cc < NCH; cc++) {
        int p = t * NCH + cc;
        s += Sl[p] * wexp[p];
      }
      iSb[t] = 1.0f / s;
    }
    __syncthreads();
    {  // ss[b][h] -> st (overwrites WA staging; fold is done)
      int bb = t >> 3, hg = t & 7;
      float acc[8];
      #pragma unroll
      for (int jj = 0; jj < 8; jj++) acc[jj] = 0.f;
      for (int cc = 0; cc < NCH; cc++) {
        int p = bb * NCH + cc;
        float wgt = wexp[p];
        const float* vp = ws + WS_V + p * 64 + hg;
        #pragma unroll
        for (int jj = 0; jj < 8; jj++) acc[jj] += wgt * vp[jj * 8];
      }
      float is = iSb[bb];
      #pragma unroll
      for (int jj = 0; jj < 8; jj++) st[bb * 66 + hg + 8 * jj] = acc[jj] * is;
    }
    __syncthreads();

    for (int r = 0; r < 4; r++) {
      {
        int bb = t >> 3, hg = t & 7;
        float acc[8];
        #pragma unroll
        for (int jj = 0; jj < 8; jj++) acc[jj] = bAVs[hg + 8 * jj];
        for (int k = 0; k < 64; k++) {
          float v = st[bb * 66 + k];
          const float* wp = WAVT + k * 64 + hg;
          #pragma unroll
          for (int jj = 0; jj < 8; jj++) acc[jj] += v * wp[8 * jj];
        }
        #pragma unroll
        for (int jj = 0; jj < 8; jj++) zs[bb * 66 + hg + 8 * jj] = acc[jj];
      }
      __syncthreads();
      if (t < 64) {
        float s1 = 0.f;
        for (int bb2 = 0; bb2 < BB; bb2++) s1 += zs[bb2 * 66 + t];
        float mu = s1 * (1.0f / BB);
        float s2 = 0.f;
        for (int bb2 = 0; bb2 < BB; bb2++) {
          float d = zs[bb2 * 66 + t] - mu;
          s2 += d * d;
        }
        float inv = gamma[t] / sqrtf(s2 * (1.0f / BB) + BN_EPS);
        scs[t] = inv;
        shs[t] = beta[t] - mu * inv;
      }
      __syncthreads();
      for (int e = t; e < BB * 64; e += 256) {
        int bb2 = e >> 6, hh = e & 63;
        st[bb2 * 66 + hh] = fmaxf(zs[bb2 * 66 + hh] * scs[hh] + shs[hh], 0.f);
      }
      __syncthreads();
    }

    if (t < BB) {
      const float* nr = st + t * 66;
      float m = bmu[0], sg = bsig[0];
      #pragma unroll 8
      for (int h = 0; h < 64; h++) {
        float v = nr[h];
        m += v * Wmu[h];
        sg += v * Wsig[h];
      }
      out[t] = m;
      out[BB + t] = sg * sg + 0.01f;
    }
  }
}

// ================================================================ launch
extern "C" void kernel_launch(void* const* d_in, const int* in_sizes, int n_in,
                              void* d_out, int out_size, void* d_ws, size_t ws_size,
                              hipStream_t stream) {
  const float* xx   = (const float*)d_in[0];
  const float* yy   = (const float*)d_in[1];
  const float* oxx  = (const float*)d_in[2];
  const float* W1   = (const float*)d_in[3];
  const float* b1   = (const float*)d_in[4];
  const float* W2   = (const float*)d_in[5];
  const float* b2   = (const float*)d_in[6];
  const float* Wenc = (const float*)d_in[7];
  const float* benc = (const float*)d_in[8];
  // d_in[9]=WQ, [10]=bQ, [15]=wQKq, [17]=bQK, [12]=bK: provably unused
  // (i-dependent score term constant over softmax axis; bK·wQKk cancels).
  const float* WK   = (const float*)d_in[11];
  const float* WV   = (const float*)d_in[13];
  const float* bV   = (const float*)d_in[14];
  const float* wQKk = (const float*)d_in[16];
  const float* WA   = (const float*)d_in[18];
  const float* bA   = (const float*)d_in[19];
  const float* gamma= (const float*)d_in[20];
  const float* beta = (const float*)d_in[21];
  const float* Wmu  = (const float*)d_in[22];
  const float* bmu  = (const float*)d_in[23];
  const float* Wsig = (const float*)d_in[24];
  const float* bsig = (const float*)d_in[25];

  float* ws = (float*)d_ws;
  unsigned int* cnt = (unsigned int*)((char*)d_ws + CNT_BYTE_OFF);
  float* out = (float*)d_out;

  hipMemsetAsync(cnt, 0, 4, stream);   // zero the done-counter (graph-safe)
  k_fused<<<NBLK, 256, 0, stream>>>(xx, yy, oxx, W1, b1, W2, b2, Wenc, benc,
                                    WK, wQKk, WV, bV, WA, bA, gamma, beta,
                                    Wmu, bmu, Wsig, bsig, ws, cnt, out);
}

// Round 4
// 148.911 us; speedup vs baseline: 1.3896x; 1.3896x over previous
//
#include <hip/hip_runtime.h>
#include <math.h>

// Problem constants
#define NIN   1535
#define NN    1536
#define BB    32
#define BN_EPS 1e-5f
#define CH    64               // rows per chunk
#define NCH   24               // chunks per batch
#define NBLK  (BB * NCH)       // 768 encode blocks (+1 fold block)

// Workspace layout (floats): M[768], S[768], vec[768][64], WAVT[4096], bAV[64]
#define WS_M    0
#define WS_S    768
#define WS_V    1536
#define WS_WAVT 50688
#define WS_BAV  54784

__device__ __forceinline__ float rdlane(float v, int l) {
  return __int_as_float(__builtin_amdgcn_readlane(__float_as_int(v), l));
}

// ================================================================ k_main
// Blocks 0..767: encode one 64-row chunk (fc1+relu, fc2+relu; output node
// uses the enc layer), per-row score sk = h2·u (the q-side score term is
// constant over the softmax axis and cancels; so does bK·wQKk), and an
// ONLINE-softmax partial (m, sum_e, sum_e*h2) kept in registers per wave,
// combined across the 4 waves at the end. No W2/h2 LDS staging at all:
// W2 rows live in VGPRs, h1 broadcast via v_readlane (VALU pipe, not LDS).
// Block 768: folds WAVT = (WA@WV)^T and bAV = bA + WA@bV into ws,
// fully hidden behind the 768 encode blocks.
__global__ __launch_bounds__(256) void k_main(
    const float* __restrict__ xx, const float* __restrict__ yy,
    const float* __restrict__ oxx,
    const float* __restrict__ W1, const float* __restrict__ b1,
    const float* __restrict__ W2, const float* __restrict__ b2,
    const float* __restrict__ Wenc, const float* __restrict__ benc,
    const float* __restrict__ WK, const float* __restrict__ wQKk,
    const float* __restrict__ WV, const float* __restrict__ bV,
    const float* __restrict__ WA, const float* __restrict__ bA,
    float* __restrict__ ws) {
  __shared__ float xs[512];            // [64 rows][8]
  __shared__ float ys[64];
  __shared__ float us[64];             // u = WK^T @ wQKk
  __shared__ float cm[4], cs[4];       // per-wave online-softmax m, s
  __shared__ float cvec[4][64];        // per-wave sum_e*h2

  const int t = threadIdx.x;
  const int blk = blockIdx.x;

  if (blk == NBLK) {                   // ---- concurrent weight-fold block
    int kg = t >> 6, h = t & 63;
    float acc[16];
    #pragma unroll
    for (int kk = 0; kk < 16; kk++) acc[kk] = 0.f;
    for (int m = 0; m < 64; m++) {
      float wa = WA[h * 64 + m];                       // per-lane row, L1-hot
      const float4* wv = (const float4*)(WV + m * 64 + kg * 16); // uniform
      float4 w0 = wv[0], w1 = wv[1], w2 = wv[2], w3 = wv[3];
      acc[0]  += wa * w0.x; acc[1]  += wa * w0.y; acc[2]  += wa * w0.z; acc[3]  += wa * w0.w;
      acc[4]  += wa * w1.x; acc[5]  += wa * w1.y; acc[6]  += wa * w1.z; acc[7]  += wa * w1.w;
      acc[8]  += wa * w2.x; acc[9]  += wa * w2.y; acc[10] += wa * w2.z; acc[11] += wa * w2.w;
      acc[12] += wa * w3.x; acc[13] += wa * w3.y; acc[14] += wa * w3.z; acc[15] += wa * w3.w;
    }
    #pragma unroll
    for (int kk = 0; kk < 16; kk++)
      ws[WS_WAVT + (kg * 16 + kk) * 64 + h] = acc[kk];
    if (t < 64) {
      float a = bA[t];
      #pragma unroll
      for (int k = 0; k < 64; k++) a += WA[t * 64 + k] * bV[k];
      ws[WS_BAV + t] = a;
    }
    return;
  }

  const int b = blk & 31;
  const int c = blk >> 5;
  const int pp = b * NCH + c;

  // ---- stage inputs (coalesced) + compute u ----
  for (int e = t; e < 512; e += 256) {
    int j = e >> 3, k = e & 7;
    int r0 = c * CH + j;
    xs[e] = (r0 < NIN) ? xx[((size_t)b * NIN + r0) * 8 + k] : oxx[b * 8 + k];
  }
  if (t < 64) {
    int r0 = c * CH + t;
    ys[t] = (r0 < NIN) ? yy[b * NIN + r0] : 0.f;
    float a = 0.f;
    #pragma unroll
    for (int h0 = 0; h0 < 64; h0++) a += wQKk[h0] * WK[h0 * 64 + t];
    us[t] = a;
  }
  __syncthreads();

  const int w = t >> 6, lane = t & 63;

  // ---- per-lane register-resident weights ----
  float w2r[64];                       // W2 row `lane` (its fc2 column)
  {
    const float4* wr = (const float4*)(W2 + lane * 64);
    #pragma unroll
    for (int q = 0; q < 16; q++) {
      float4 v = wr[q];
      w2r[4 * q] = v.x; w2r[4 * q + 1] = v.y;
      w2r[4 * q + 2] = v.z; w2r[4 * q + 3] = v.w;
    }
  }
  float w1r[9];
  #pragma unroll
  for (int i = 0; i < 9; i++) w1r[i] = W1[lane * 9 + i];
  const float b1v = b1[lane], b2v = b2[lane], uv = us[lane];

  // ---- 16 rows per wave, online softmax in registers ----
  float m_run = -1e30f, s_run = 0.f, acc_v = 0.f;
  for (int rr = 0; rr < 16; rr++) {
    int j = w * 16 + rr;
    int r0 = c * CH + j;
    float4 x0 = *(const float4*)(xs + j * 8);     // broadcast reads
    float4 x1 = *(const float4*)(xs + j * 8 + 4);
    float h2;
    if (r0 < NIN) {                               // wave-uniform branch
      float a = b1v;
      a += x0.x * w1r[0] + x0.y * w1r[1] + x0.z * w1r[2] + x0.w * w1r[3];
      a += x1.x * w1r[4] + x1.y * w1r[5] + x1.z * w1r[6] + x1.w * w1r[7];
      a += ys[j] * w1r[8];
      float h1v = fmaxf(a, 0.f);
      float a0 = b2v, a1 = 0.f, a2 = 0.f, a3 = 0.f;
      #pragma unroll
      for (int k = 0; k < 64; k += 4) {           // h1 broadcast on VALU pipe
        a0 += rdlane(h1v, k)     * w2r[k];
        a1 += rdlane(h1v, k + 1) * w2r[k + 1];
        a2 += rdlane(h1v, k + 2) * w2r[k + 2];
        a3 += rdlane(h1v, k + 3) * w2r[k + 3];
      }
      h2 = fmaxf((a0 + a1) + (a2 + a3), 0.f);
    } else {                                      // output node: enc layer
      const float4* we = (const float4*)(Wenc + lane * 8);
      float4 w0 = we[0], w1v = we[1];
      float a = benc[lane];
      a += x0.x * w0.x + x0.y * w0.y + x0.z * w0.z + x0.w * w0.w;
      a += x1.x * w1v.x + x1.y * w1v.y + x1.z * w1v.z + x1.w * w1v.w;
      h2 = fmaxf(a, 0.f);
    }
    // score (butterfly: every lane gets the full dot)
    float p = h2 * uv;
    p += __shfl_xor(p, 1);  p += __shfl_xor(p, 2);  p += __shfl_xor(p, 4);
    p += __shfl_xor(p, 8);  p += __shfl_xor(p, 16); p += __shfl_xor(p, 32);
    // online softmax update
    float mn = fmaxf(m_run, p);
    float f  = __expf(m_run - mn);
    float e  = __expf(p - mn);
    s_run = s_run * f + e;
    acc_v = acc_v * f + e * h2;
    m_run = mn;
  }

  // ---- combine 4 waves, write chunk partial ----
  if (lane == 0) { cm[w] = m_run; cs[w] = s_run; }
  cvec[w][lane] = acc_v;
  __syncthreads();
  if (t < 64) {
    float M = fmaxf(fmaxf(cm[0], cm[1]), fmaxf(cm[2], cm[3]));
    float f0 = __expf(cm[0] - M), f1 = __expf(cm[1] - M);
    float f2 = __expf(cm[2] - M), f3 = __expf(cm[3] - M);
    ws[WS_V + pp * 64 + t] = f0 * cvec[0][t] + f1 * cvec[1][t] +
                             f2 * cvec[2][t] + f3 * cvec[3][t];
    if (t == 0) {
      ws[WS_M + pp] = M;
      ws[WS_S + pp] = f0 * cs[0] + f1 * cs[1] + f2 * cs[2] + f3 * cs[3];
    }
  }
}

// ================================================================ k_tail
// One block: load pre-folded WAVT/bAV, combine softmax partials, round-1
// z = ss@WAV^T + bAV, rounds 2..4 (identical nodes -> uniform softmax is
// identity) + BN + relu, heads.
__global__ __launch_bounds__(256) void k_tail(
    const float* __restrict__ ws,
    const float* __restrict__ gamma, const float* __restrict__ beta,
    const float* __restrict__ Wmu, const float* __restrict__ bmu,
    const float* __restrict__ Wsig, const float* __restrict__ bsig,
    float* __restrict__ out) {
  __shared__ float WAVT[4096];     // WAVT[k][h]
  __shared__ float bAVs[64];
  __shared__ float Ml[768], Sl[768], wexp[768];
  __shared__ float Mb[32], iSb[32];
  __shared__ float st[32 * 66];    // stride 66 -> conflict-free
  __shared__ float zs[32 * 66];
  __shared__ float scs[64], shs[64];
  const int t = threadIdx.x;

  for (int e = t; e < 4096; e += 256) WAVT[e] = ws[WS_WAVT + e];
  if (t < 64) bAVs[t] = ws[WS_BAV + t];
  for (int p = t; p < 768; p += 256) {
    Ml[p] = ws[WS_M + p];
    Sl[p] = ws[WS_S + p];
  }
  __syncthreads();

  if (t < 32) {
    float m = -1e30f;
    for (int cc = 0; cc < NCH; cc++) m = fmaxf(m, Ml[t * NCH + cc]);
    Mb[t] = m;
  }
  __syncthreads();
  for (int p = t; p < 768; p += 256) wexp[p] = __expf(Ml[p] - Mb[p / NCH]);
  __syncthreads();
  if (t < 32) {
    float s = 0.f;
    for (int cc = 0; cc < NCH; cc++) {
      int p = t * NCH + cc;
      s += Sl[p] * wexp[p];
    }
    iSb[t] = 1.0f / s;
  }
  __syncthreads();
  {  // ss[b][h] = (sum_c wexp * vec_c[h]) / S_b
    int bb = t >> 3, hg = t & 7;
    float acc[8];
    #pragma unroll
    for (int jj = 0; jj < 8; jj++) acc[jj] = 0.f;
    for (int cc = 0; cc < NCH; cc++) {
      int p = bb * NCH + cc;
      float wgt = wexp[p];
      const float* vp = ws + WS_V + p * 64 + hg;
      #pragma unroll
      for (int jj = 0; jj < 8; jj++) acc[jj] += wgt * vp[jj * 8];
    }
    float is = iSb[bb];
    #pragma unroll
    for (int jj = 0; jj < 8; jj++) st[bb * 66 + hg + 8 * jj] = acc[jj] * is;
  }
  __syncthreads();

  for (int r = 0; r < 4; r++) {
    {
      int bb = t >> 3, hg = t & 7;
      float acc[8];
      #pragma unroll
      for (int jj = 0; jj < 8; jj++) acc[jj] = bAVs[hg + 8 * jj];
      for (int k = 0; k < 64; k++) {
        float v = st[bb * 66 + k];
        const float* wp = WAVT + k * 64 + hg;
        #pragma unroll
        for (int jj = 0; jj < 8; jj++) acc[jj] += v * wp[8 * jj];
      }
      #pragma unroll
      for (int jj = 0; jj < 8; jj++) zs[bb * 66 + hg + 8 * jj] = acc[jj];
    }
    __syncthreads();
    if (t < 64) {
      float s1 = 0.f;
      for (int bb2 = 0; bb2 < BB; bb2++) s1 += zs[bb2 * 66 + t];
      float mu = s1 * (1.0f / BB);
      float s2 = 0.f;
      for (int bb2 = 0; bb2 < BB; bb2++) {
        float d = zs[bb2 * 66 + t] - mu;
        s2 += d * d;
      }
      float inv = gamma[t] / sqrtf(s2 * (1.0f / BB) + BN_EPS);
      scs[t] = inv;
      shs[t] = beta[t] - mu * inv;
    }
    __syncthreads();
    for (int e = t; e < BB * 64; e += 256) {
      int bb2 = e >> 6, hh = e & 63;
      st[bb2 * 66 + hh] = fmaxf(zs[bb2 * 66 + hh] * scs[hh] + shs[hh], 0.f);
    }
    __syncthreads();
  }

  if (t < BB) {   // agg = max over identical nodes = state itself
    const float* nr = st + t * 66;
    float m = bmu[0], sg = bsig[0];
    #pragma unroll 8
    for (int h = 0; h < 64; h++) {
      float v = nr[h];
      m += v * Wmu[h];
      sg += v * Wsig[h];
    }
    out[t] = m;
    out[BB + t] = sg * sg + 0.01f;
  }
}

// ================================================================ launch
extern "C" void kernel_launch(void* const* d_in, const int* in_sizes, int n_in,
                              void* d_out, int out_size, void* d_ws, size_t ws_size,
                              hipStream_t stream) {
  const float* xx   = (const float*)d_in[0];
  const float* yy   = (const float*)d_in[1];
  const float* oxx  = (const float*)d_in[2];
  const float* W1   = (const float*)d_in[3];
  const float* b1   = (const float*)d_in[4];
  const float* W2   = (const float*)d_in[5];
  const float* b2   = (const float*)d_in[6];
  const float* Wenc = (const float*)d_in[7];
  const float* benc = (const float*)d_in[8];
  // d_in[9]=WQ, [10]=bQ, [15]=wQKq, [17]=bQK, [12]=bK: provably unused
  // (q-side score term constant over softmax axis; bK·wQKk cancels).
  const float* WK   = (const float*)d_in[11];
  const float* WV   = (const float*)d_in[13];
  const float* bV   = (const float*)d_in[14];
  const float* wQKk = (const float*)d_in[16];
  const float* WA   = (const float*)d_in[18];
  const float* bA   = (const float*)d_in[19];
  const float* gamma= (const float*)d_in[20];
  const float* beta = (const float*)d_in[21];
  const float* Wmu  = (const float*)d_in[22];
  const float* bmu  = (const float*)d_in[23];
  const float* Wsig = (const float*)d_in[24];
  const float* bsig = (const float*)d_in[25];

  float* ws  = (float*)d_ws;
  float* out = (float*)d_out;

  k_main<<<NBLK + 1, 256, 0, stream>>>(xx, yy, oxx, W1, b1, W2, b2, Wenc, benc,
                                       WK, wQKk, WV, bV, WA, bA, ws);
  k_tail<<<1, 256, 0, stream>>>(ws, gamma, beta, Wmu, bmu, Wsig, bsig, out);
}